// Round 1
// baseline (92.216 us; speedup 1.0000x reference)
//
#include <hip/hip_runtime.h>
#include <hip/hip_bf16.h>

// RightPool = cumulative max along last axis (W=128) of (16,256,128,128) f32.
// Memory-bound: 512 MiB total traffic -> ~85us floor at 6.3 TB/s.
//
// Layout: each 128-float row handled by a 32-lane group; 2 rows per wave64.
// Lane l loads float4 covering elements [4l, 4l+4) -> wave reads 1024
// contiguous bytes (fully coalesced). Local cummax in-register, then 5-step
// shfl_up max-scan across the 32-lane segment, apply exclusive prefix, store.

__global__ void __launch_bounds__(256) rightpool_kernel(
    const float* __restrict__ x, float* __restrict__ out, long long nrows) {
    const int lane = threadIdx.x & 63;
    const int half = lane >> 5;   // which row within the wave
    const int l    = lane & 31;   // lane within the 32-lane row group

    const long long wave = (long long)blockIdx.x * (blockDim.x >> 6) + (threadIdx.x >> 6);
    const long long row  = wave * 2 + half;
    if (row >= nrows) return;

    const float4* src = reinterpret_cast<const float4*>(x + row * 128) + l;
    float4 v = *src;

    // cummax within the float4
    v.y = fmaxf(v.y, v.x);
    v.z = fmaxf(v.z, v.y);
    v.w = fmaxf(v.w, v.z);

    // inclusive max-scan of per-lane max across the 32-lane segment.
    // Guard l >= d keeps the scan from crossing the 32-lane row boundary
    // even though shfl width is 64.
    float m = v.w;
    #pragma unroll
    for (int d = 1; d < 32; d <<= 1) {
        float o = __shfl_up(m, d, 64);
        if (l >= d) m = fmaxf(m, o);
    }

    // exclusive prefix for this lane's 4 elements
    float e = __shfl_up(m, 1, 64);
    if (l == 0) e = -__builtin_inff();

    v.x = fmaxf(v.x, e);
    v.y = fmaxf(v.y, e);
    v.z = fmaxf(v.z, e);
    v.w = fmaxf(v.w, e);

    float4* dst = reinterpret_cast<float4*>(out + row * 128) + l;
    *dst = v;
}

extern "C" void kernel_launch(void* const* d_in, const int* in_sizes, int n_in,
                              void* d_out, int out_size, void* d_ws, size_t ws_size,
                              hipStream_t stream) {
    const float* x = (const float*)d_in[0];
    float* out = (float*)d_out;
    const long long nrows = (long long)in_sizes[0] / 128;  // 524288 rows of 128 floats

    // 32 threads per row, 2 rows per wave, 256 threads/block -> 8 rows/block
    const long long total_threads = nrows * 32;
    const int block = 256;
    const int grid = (int)((total_threads + block - 1) / block);

    rightpool_kernel<<<grid, block, 0, stream>>>(x, out, nrows);
}

// Round 3
// 84.712 us; speedup vs baseline: 1.0886x; 1.0886x over previous
//
#include <hip/hip_runtime.h>
#include <hip/hip_bf16.h>

// RightPool = cumulative max along last axis (W=128) of (16,256,128,128) f32.
// Memory-bound: 536.9 MB total traffic. Measured fill ceiling on this chip:
// ~7.0 TB/s; copy ceiling ~6.3 TB/s -> floor ~77-85us.
//
// Layout: each 128-float row handled by a 32-lane group; 2 rows per wave64.
// Lane l loads float4 covering elements [4l, 4l+4) -> wave reads 1024
// contiguous bytes (fully coalesced). Nontemporal load/store (via clang
// ext_vector — HIP's float4 class is rejected by the builtin): both streams
// are touch-once, so skip cache allocation. Scan uses width-32 shuffles
// (hardware-clamped within the 32-lane segment -> no guard branches).

typedef float f32x4 __attribute__((ext_vector_type(4)));

__global__ void __launch_bounds__(256) rightpool_kernel(
    const float* __restrict__ x, float* __restrict__ out, long long nrows) {
    const int lane = threadIdx.x & 63;
    const int half = lane >> 5;   // which row within the wave
    const int l    = lane & 31;   // lane within the 32-lane row group

    const long long wave = (long long)blockIdx.x * (blockDim.x >> 6) + (threadIdx.x >> 6);
    const long long row  = wave * 2 + half;
    if (row >= nrows) return;

    const f32x4* src = reinterpret_cast<const f32x4*>(x + row * 128) + l;
    f32x4 v = __builtin_nontemporal_load(src);

    // cummax within the float4
    v.y = fmaxf(v.y, v.x);
    v.z = fmaxf(v.z, v.y);
    v.w = fmaxf(v.w, v.z);

    // inclusive max-scan across the 32-lane segment; width=32 clamps at the
    // segment boundary (out-of-range lanes get their own value -> fmax no-op).
    float m = v.w;
    #pragma unroll
    for (int d = 1; d < 32; d <<= 1) {
        float o = __shfl_up(m, d, 32);
        m = fmaxf(m, o);
    }

    // exclusive prefix for this lane's 4 elements
    float e = __shfl_up(m, 1, 32);
    if (l == 0) e = -__builtin_inff();

    v.x = fmaxf(v.x, e);
    v.y = fmaxf(v.y, e);
    v.z = fmaxf(v.z, e);
    v.w = fmaxf(v.w, e);

    f32x4* dst = reinterpret_cast<f32x4*>(out + row * 128) + l;
    __builtin_nontemporal_store(v, dst);
}

extern "C" void kernel_launch(void* const* d_in, const int* in_sizes, int n_in,
                              void* d_out, int out_size, void* d_ws, size_t ws_size,
                              hipStream_t stream) {
    const float* x = (const float*)d_in[0];
    float* out = (float*)d_out;
    const long long nrows = (long long)in_sizes[0] / 128;  // 524288 rows of 128 floats

    // 32 threads per row, 2 rows per wave, 256 threads/block -> 8 rows/block
    const long long total_threads = nrows * 32;
    const int block = 256;
    const int grid = (int)((total_threads + block - 1) / block);

    rightpool_kernel<<<grid, block, 0, stream>>>(x, out, nrows);
}